// Round 1
// baseline (382.572 us; speedup 1.0000x reference)
//
#include <hip/hip_runtime.h>

// 3x3 valid conv (NCHW/OIHW) + bias + relu(y)*min(y+3,6)/6, fp32.
// x: (N=4096, C=3, 32, 32), w: (16, 3, 3, 3), out: (N, 16, 30, 30).
//
// Round 5 design (vs R4 @ ~141us kernel-side):
//  - Weights/bias OFF the LDS pipe entirely: read from global with
//    compile-time-constant, wave-uniform indices -> compiler scalarizes to
//    s_load into SGPRs (SMEM/K$ pipe), and v_fmac reads the SGPR operand
//    directly. R4 spent ~108 ds_read_b128 broadcasts/wave (~1KB RF write
//    each) on the single per-CU LDS pipe; that congestion + the sxoff-table
//    serial chain is the theory for the invariant ~141us.
//  - No sxoff LDS table: position loop = dynamic ic (3) x fully-unrolled 9
//    static (kh,kw) positions; x offsets are affine in ic (pure VALU/SALU,
//    no LDS dependency), so the scheduler can batch-issue loads and overlap
//    iterations.
//  - LDS = 12KB image only; one barrier total.
//  - Weight VGPRs freed -> ~90 VGPR -> __launch_bounds__(256,5):
//    5 waves/SIMD (20 waves/CU, 5 blocks/CU) instead of R4's 4.
//  - Same pixel mapping as R4: p = tid + k*256 (stride-1 LDS x-reads across
//    lanes, max 3-way bank alias = ~free; coalesced scalar stores).

__global__ __launch_bounds__(256, 5) void conv3x3_hswish(
    const float* __restrict__ x,
    const float* __restrict__ w,
    const float* __restrict__ bias,
    float* __restrict__ out)
{
    const int n = blockIdx.x;
    const int tid = threadIdx.x;

    __shared__ __align__(16) float sx[3072];   // image, 12 KB

    // Stage image: 768 float4s, 3 per thread, fully coalesced.
    {
        const float4* xg = (const float4*)(x + (size_t)n * 3072);
        float4* s4 = (float4*)sx;
        #pragma unroll
        for (int i = 0; i < 3; ++i) s4[tid + i * 256] = xg[tid + i * 256];
    }
    __syncthreads();

    // Pixel k of this thread: p = tid + k*256 (flattened oh*30+ow), <900.
    int xb[4];
    #pragma unroll
    for (int k = 0; k < 4; ++k) {
        const int p = tid + k * 256;
        const int pc = p < 900 ? p : 899;   // dead slots clamp reads
        const int oh = pc / 30;
        xb[k] = oh * 32 + (pc - oh * 30);
    }

    float acc[4][16];
    #pragma unroll
    for (int k = 0; k < 4; ++k)
        #pragma unroll
        for (int oc = 0; oc < 16; ++oc) acc[k][oc] = 0.f;

    // Hot loop: dynamic ic, static (kh,kw). All weight indices are
    // compile-time offsets from the uniform pointer wq -> s_load/SGPR.
    #pragma unroll 1
    for (int ic = 0; ic < 3; ++ic) {
        const float* __restrict__ wq = w + ic * 9;
        const int xbase = ic << 10;          // ic*1024
        #pragma unroll
        for (int kh = 0; kh < 3; ++kh) {
            #pragma unroll
            for (int kw = 0; kw < 3; ++kw) {
                float ws[16];
                #pragma unroll
                for (int oc = 0; oc < 16; ++oc)
                    ws[oc] = wq[oc * 27 + kh * 3 + kw];   // uniform -> SGPR
                const int xoff = xbase + kh * 32 + kw;
                #pragma unroll
                for (int k = 0; k < 4; ++k) {
                    const float xv = sx[xoff + xb[k]];    // only LDS traffic
                    #pragma unroll
                    for (int oc = 0; oc < 16; ++oc)
                        acc[k][oc] = fmaf(xv, ws[oc], acc[k][oc]);
                }
            }
        }
    }

    // Epilogue: bias (scalar loads) + hardswish*relu, coalesced stores.
    float bb[16];
    #pragma unroll
    for (int oc = 0; oc < 16; ++oc) bb[oc] = bias[oc];    // uniform -> SGPR

    float* outn = out + (size_t)n * 14400;
    #pragma unroll
    for (int k = 0; k < 4; ++k) {
        const int p = tid + k * 256;
        if (p < 900) {
            #pragma unroll
            for (int oc = 0; oc < 16; ++oc) {
                const float y = acc[k][oc] + bb[oc];
                // relu(y) * min(y+3,6)/6 == max(y,0) * min(y/6+0.5, 1)
                const float r = fmaxf(y, 0.f) * fminf(fmaf(y, 1.f / 6.f, 0.5f), 1.f);
                outn[oc * 900 + p] = r;
            }
        }
    }
}

extern "C" void kernel_launch(void* const* d_in, const int* in_sizes, int n_in,
                              void* d_out, int out_size, void* d_ws, size_t ws_size,
                              hipStream_t stream) {
    const float* x    = (const float*)d_in[0];
    const float* w    = (const float*)d_in[1];
    const float* bias = (const float*)d_in[2];
    float* out        = (float*)d_out;

    const int N = in_sizes[0] / (3 * 32 * 32);  // 4096
    conv3x3_hswish<<<N, 256, 0, stream>>>(x, w, bias, out);
}

// Round 2
// 285.978 us; speedup vs baseline: 1.3378x; 1.3378x over previous
//
#include <hip/hip_runtime.h>

// 3x3 valid conv (NCHW/OIHW) + bias + relu(y)*min(y+3,6)/6, fp32.
// x: (N=4096, C=3, 32, 32), w: (16, 3, 3, 3), out: (N, 16, 30, 30).
//
// Round 6 design (vs R5 @ 171us conv dispatch):
//  - R5 post-mortem: __launch_bounds__(256,5) capped VGPRs at ~96 < the 64
//    live accumulators + temps -> acc churn (VGPR_Count=48 reported, VALUBusy
//    56% vs 13% FMA floor). Restored to (256,4).
//  - rocprof showed 2.4x write amplification (564 MB vs 236 MB ideal) and
//    2.5x fetch amplification (127 vs 50 MB): per-lane dword stores at
//    oc*3600B offsets (=16 mod 64) straddle partial 64B lines completed by
//    other waves later -> write-allocate fetch + double flush. Fix: stage
//    each 256-pixel chunk into LDS sy[16][256] (activated+biased), then
//    store float4 per lane -> every wave store is 1KB of complete, aligned
//    64B lines, written exactly once.
//  - Weights/bias stay on the scalar path (s_load -> SGPR, v_fmac v,s,v):
//    that part of R5 worked (SGPR=112) and keeps the LDS pipe for x reads.
//  - LDS: 12KB sx + 16KB sy = 28KB -> still 4-5 blocks/CU.

__global__ __launch_bounds__(256, 4) void conv3x3_hswish(
    const float* __restrict__ x,
    const float* __restrict__ w,
    const float* __restrict__ bias,
    float* __restrict__ out)
{
    const int n = blockIdx.x;
    const int tid = threadIdx.x;

    __shared__ __align__(16) float sx[3072];   // image, 12 KB
    __shared__ __align__(16) float sy[4096];   // epilogue staging, 16 KB

    // Stage image: 768 float4s, 3 per thread, fully coalesced.
    {
        const float4* xg = (const float4*)(x + (size_t)n * 3072);
        float4* s4 = (float4*)sx;
        #pragma unroll
        for (int i = 0; i < 3; ++i) s4[tid + i * 256] = xg[tid + i * 256];
    }
    __syncthreads();

    // Pixel k of this thread: p = tid + k*256 (flattened oh*30+ow), <900.
    int xb[4];
    #pragma unroll
    for (int k = 0; k < 4; ++k) {
        const int p = tid + k * 256;
        const int pc = p < 900 ? p : 899;   // dead slots clamp reads
        const int oh = pc / 30;
        xb[k] = oh * 32 + (pc - oh * 30);
    }

    float acc[4][16];
    #pragma unroll
    for (int k = 0; k < 4; ++k)
        #pragma unroll
        for (int oc = 0; oc < 16; ++oc) acc[k][oc] = 0.f;

    // Hot loop: dynamic ic, static (kh,kw). Weight indices are compile-time
    // offsets from the uniform pointer wq -> s_load/SGPR.
    #pragma unroll 1
    for (int ic = 0; ic < 3; ++ic) {
        const float* __restrict__ wq = w + ic * 9;
        const int xbase = ic << 10;          // ic*1024
        #pragma unroll
        for (int kh = 0; kh < 3; ++kh) {
            #pragma unroll
            for (int kw = 0; kw < 3; ++kw) {
                float ws[16];
                #pragma unroll
                for (int oc = 0; oc < 16; ++oc)
                    ws[oc] = wq[oc * 27 + kh * 3 + kw];   // uniform -> SGPR
                const int xoff = xbase + kh * 32 + kw;
                #pragma unroll
                for (int k = 0; k < 4; ++k) {
                    const float xv = sx[xoff + xb[k]];    // only LDS traffic
                    #pragma unroll
                    for (int oc = 0; oc < 16; ++oc)
                        acc[k][oc] = fmaf(xv, ws[oc], acc[k][oc]);
                }
            }
        }
    }

    // Bias via scalar path.
    float bb[16];
    #pragma unroll
    for (int oc = 0; oc < 16; ++oc) bb[oc] = bias[oc];

    // Epilogue: per 256-pixel chunk, stage activated results to LDS, then
    // store as aligned float4 (full 64B lines, one writer per line).
    float* outn = out + (size_t)n * 14400;
    #pragma unroll
    for (int k = 0; k < 4; ++k) {
        __syncthreads();                    // sy free for reuse
        const int p = tid + k * 256;
        if (p < 900) {
            #pragma unroll
            for (int oc = 0; oc < 16; ++oc) {
                const float y = acc[k][oc] + bb[oc];
                // relu(y) * min(y+3,6)/6 == max(y,0) * min(y/6+0.5, 1)
                sy[oc * 256 + tid] =
                    fmaxf(y, 0.f) * fminf(fmaf(y, 1.f / 6.f, 0.5f), 1.f);
            }
        }
        __syncthreads();
        // 16 oc rows x 64 float4 slots; k=3 chunk has 132 valid pixels
        // per oc = exactly 33 float4s.
        const int lim4 = (k < 3) ? 64 : 33;
        #pragma unroll
        for (int i = 0; i < 4; ++i) {
            const int f = tid + i * 256;    // 0..1023
            const int oc = f >> 6;
            const int j = f & 63;
            if (j < lim4) {
                *(float4*)(outn + oc * 900 + k * 256 + 4 * j) =
                    *(const float4*)(sy + oc * 256 + 4 * j);
            }
        }
    }
}

extern "C" void kernel_launch(void* const* d_in, const int* in_sizes, int n_in,
                              void* d_out, int out_size, void* d_ws, size_t ws_size,
                              hipStream_t stream) {
    const float* x    = (const float*)d_in[0];
    const float* w    = (const float*)d_in[1];
    const float* bias = (const float*)d_in[2];
    float* out        = (float*)d_out;

    const int N = in_sizes[0] / (3 * 32 * 32);  // 4096
    conv3x3_hswish<<<N, 256, 0, stream>>>(x, w, bias, out);
}